// Round 9
// baseline (120.906 us; speedup 1.0000x reference)
//
#include <hip/hip_runtime.h>

// Problem constants (batch: (3, 1280, 1280) fp32, PATCH=16)
#define PS 16
#define HW 1280
#define NPS 80            // patches per side
#define NP (NPS * NPS)    // 6400 patches
#define GS 12             // floats per record: 9 gram + 1 sq + 2 pad (48B)

#define FBLK 512          // fused grid: 512 blocks x 320 threads.
                          // __launch_bounds__(320,4) => VGPR<=128 => >=3 blocks/CU
                          // capacity (768) >= grid (512): all blocks resident,
                          // grid barrier cannot deadlock.
#define TI 64             // tile rows
#define TJW 1280          // tile col window (5 waves x 64 lanes x 4 cols)
#define NBI (NP / TI)     // 100
#define NBJ (NP / TJW)    // 5
#define NTILE (NBI * NBJ) // 500

typedef float vf4 __attribute__((ext_vector_type(4)));

// ordered-uint mapping for float atomic max
__device__ __forceinline__ unsigned f2ord(float f) {
    unsigned u = __float_as_uint(f);
    return (u & 0x80000000u) ? ~u : (u | 0x80000000u);
}
__device__ __forceinline__ float ord2f(unsigned m) {
    return (m & 0x80000000u) ? __uint_as_float(m & 0x7FFFFFFFu) : __uint_as_float(~m);
}

// ---- gram: grid(1600) x 256; wave w computes patch blockIdx.x*4+w.
// Also resets mm (max accumulator) and bar (grid-barrier counter) for the
// following fused kernel — kernel boundary makes the resets visible.
__global__ __launch_bounds__(256) void gram_kernel(const float* __restrict__ x,
                                                   float* __restrict__ G,
                                                   unsigned* __restrict__ mm,
                                                   unsigned* __restrict__ bar) {
    const int t = threadIdx.x;
    if (blockIdx.x == 0 && t == 0) { mm[0] = 0u; bar[0] = 0u; }
    const int n = blockIdx.x * 4 + (t >> 6);
    const int l = t & 63;
    const int pi = n / NPS, pj = n % NPS;
    const int r = l >> 2, c = (l & 3) * 4;
    const size_t base = (size_t)(pi * PS + r) * HW + pj * PS + c;
    const float4 A = *(const float4*)(x + base);
    const float4 B = *(const float4*)(x + base + (size_t)HW * HW);
    const float4 C = *(const float4*)(x + base + 2 * (size_t)HW * HW);
    float p[6];
    p[0] = A.x * A.x + A.y * A.y + A.z * A.z + A.w * A.w;
    p[1] = A.x * B.x + A.y * B.y + A.z * B.z + A.w * B.w;
    p[2] = A.x * C.x + A.y * C.y + A.z * C.z + A.w * C.w;
    p[3] = B.x * B.x + B.y * B.y + B.z * B.z + B.w * B.w;
    p[4] = B.x * C.x + B.y * C.y + B.z * C.z + B.w * C.w;
    p[5] = C.x * C.x + C.y * C.y + C.z * C.z + C.w * C.w;
#pragma unroll
    for (int k = 0; k < 6; ++k) {
        float v = p[k];
#pragma unroll
        for (int off = 32; off; off >>= 1) v += __shfl_xor(v, off);
        p[k] = v;
    }
    if (l == 0) {
        const float sc = 1.0f / 768.0f;
        const float g0 = p[0] * sc, g1 = p[1] * sc, g2 = p[2] * sc;
        const float g3 = p[3] * sc, g4 = p[4] * sc, g5 = p[5] * sc;
        const float row[9] = {g0, g1, g2, g1, g3, g4, g2, g4, g5};
        float s = 0.f;
#pragma unroll
        for (int k = 0; k < 9; ++k) s = fmaf(row[k], row[k], s);
        float* dst = G + (size_t)n * GS;
        *(float4*)(dst)     = make_float4(row[0], row[1], row[2], row[3]);
        *(float4*)(dst + 4) = make_float4(row[4], row[5], row[6], row[7]);
        *(float4*)(dst + 8) = make_float4(row[8], s, 0.f, 0.f);
    }
}

// ---- fused max + write. Phase A: max over upper-band 64x1280 tiles
// (matrix symmetric, diag==0 => only j-window >= i0 tiles needed).
// Grid barrier: only atomics cross it (mm, bar); G is read-only here.
// Phase B: normalized write, j-fastest tile order (store linearity, r7).
__global__ __launch_bounds__(320, 4) void maxwrite_kernel(const float* __restrict__ G,
                                                          unsigned* __restrict__ mm,
                                                          unsigned* __restrict__ bar,
                                                          float* __restrict__ out) {
    const int t = threadIdx.x;
    const int w = t >> 6, l = t & 63;
    __shared__ float rg[TI * GS];   // 3 KB
    __shared__ float smax[5];
    __shared__ float sinv;

    // ---- phase A: max ----
    float vmax = -3.4e38f;
    for (int tau = blockIdx.x; tau < NTILE; tau += FBLK) {
        const int bi = tau / NBJ, bj = tau % NBJ;
        const int i0 = bi * TI, j0 = bj * TJW;
        if (i0 > j0 + TJW - 1) continue;   // block-uniform skip
        __syncthreads();
        if (t < TI * GS / 4)
            ((float4*)rg)[t] = *(const float4*)(G + (size_t)i0 * GS + t * 4);
        __syncthreads();
        const int jw = j0 + w * 256 + l * 4;
        float gj[4][10];
#pragma unroll
        for (int c = 0; c < 4; ++c) {
            const float* src = G + (size_t)(jw + c) * GS;
            const float4 a = *(const float4*)(src);
            const float4 b = *(const float4*)(src + 4);
            const float4 q = *(const float4*)(src + 8);
            gj[c][0] = a.x; gj[c][1] = a.y; gj[c][2] = a.z; gj[c][3] = a.w;
            gj[c][4] = b.x; gj[c][5] = b.y; gj[c][6] = b.z; gj[c][7] = b.w;
            gj[c][8] = q.x; gj[c][9] = q.y;
        }
#pragma unroll 4
        for (int r = 0; r < TI; ++r) {
            const float4 a = *(const float4*)(rg + r * GS);
            const float4 b = *(const float4*)(rg + r * GS + 4);
            const float4 q = *(const float4*)(rg + r * GS + 8);
            const float gi[9] = {a.x, a.y, a.z, a.w, b.x, b.y, b.z, b.w, q.x};
            const float si = q.y;
#pragma unroll
            for (int c = 0; c < 4; ++c) {
                float inner = 0.f;
#pragma unroll
                for (int k = 0; k < 9; ++k) inner = fmaf(gi[k], gj[c][k], inner);
                vmax = fmaxf(vmax, si + gj[c][9] - 2.f * inner);
            }
        }
    }
#pragma unroll
    for (int off = 32; off; off >>= 1) vmax = fmaxf(vmax, __shfl_xor(vmax, off));
    if (l == 0) smax[w] = vmax;
    __syncthreads();

    // ---- grid barrier (atomics only; deadlock-free by residency arith) ----
    if (t == 0) {
        float bm = fmaxf(fmaxf(fmaxf(smax[0], smax[1]), fmaxf(smax[2], smax[3])), smax[4]);
        atomicMax(mm, f2ord(bm));
        __threadfence();                 // make the RMW visible before arrive
        atomicAdd(bar, 1u);
        unsigned v;
        do {
            v = __hip_atomic_load(bar, __ATOMIC_ACQUIRE, __HIP_MEMORY_SCOPE_AGENT);
        } while (v < FBLK);
        sinv = 1.0f / ord2f(atomicOr(mm, 0u));   // fresh device-scope read
    }
    __syncthreads();
    const float inv = sinv;

    // ---- phase B: normalized write ----
    for (int tau = blockIdx.x; tau < NTILE; tau += FBLK) {
        const int bi = tau / NBJ, bj = tau % NBJ;
        const int i0 = bi * TI, j0 = bj * TJW;
        __syncthreads();
        if (t < TI * GS / 4)
            ((float4*)rg)[t] = *(const float4*)(G + (size_t)i0 * GS + t * 4);
        __syncthreads();
        const int jw = j0 + w * 256 + l * 4;
        float gj[4][10];
#pragma unroll
        for (int c = 0; c < 4; ++c) {
            const float* src = G + (size_t)(jw + c) * GS;
            const float4 a = *(const float4*)(src);
            const float4 b = *(const float4*)(src + 4);
            const float4 q = *(const float4*)(src + 8);
            gj[c][0] = a.x; gj[c][1] = a.y; gj[c][2] = a.z; gj[c][3] = a.w;
            gj[c][4] = b.x; gj[c][5] = b.y; gj[c][6] = b.z; gj[c][7] = b.w;
            gj[c][8] = q.x; gj[c][9] = q.y;
        }
        float* dst = out + (size_t)i0 * NP + jw;
#pragma unroll 4
        for (int r = 0; r < TI; ++r) {
            const float4 a = *(const float4*)(rg + r * GS);
            const float4 b = *(const float4*)(rg + r * GS + 4);
            const float4 q = *(const float4*)(rg + r * GS + 8);
            const float gi[9] = {a.x, a.y, a.z, a.w, b.x, b.y, b.z, b.w, q.x};
            const float si = q.y;
            vf4 dv;
#pragma unroll
            for (int c = 0; c < 4; ++c) {
                float inner = 0.f;
#pragma unroll
                for (int k = 0; k < 9; ++k) inner = fmaf(gi[k], gj[c][k], inner);
                dv[c] = (si + gj[c][9] - 2.f * inner) * inv;
            }
            *(vf4*)dst = dv;
            dst += NP;
        }
    }
}

extern "C" void kernel_launch(void* const* d_in, const int* in_sizes, int n_in,
                              void* d_out, int out_size, void* d_ws, size_t ws_size,
                              hipStream_t stream) {
    (void)in_sizes; (void)n_in; (void)out_size; (void)ws_size;
    const float* x = (const float*)d_in[0];
    float* out = (float*)d_out;
    float* G = (float*)d_ws;                                       // 300 KiB
    unsigned* mm = (unsigned*)((char*)d_ws + (size_t)NP * GS * sizeof(float));
    unsigned* bar = mm + 1;

    gram_kernel<<<NP / 4, 256, 0, stream>>>(x, G, mm, bar);
    maxwrite_kernel<<<FBLK, 320, 0, stream>>>(G, mm, bar, out);
}

// Round 10
// 67.925 us; speedup vs baseline: 1.7800x; 1.7800x over previous
//
#include <hip/hip_runtime.h>

// Problem constants (batch: (3, 1280, 1280) fp32, PATCH=16)
#define PS 16
#define HW 1280
#define NPS 80            // patches per side
#define NP (NPS * NPS)    // 6400 patches
#define GS 12             // floats per record: 9 gram + 1 sq + 2 pad (48B)
#define NT32 (NP / 32)    // 200 32-record tiles

typedef float vf4 __attribute__((ext_vector_type(4)));
typedef short bf16x8 __attribute__((ext_vector_type(8)));
typedef float f32x16 __attribute__((ext_vector_type(16)));

// ordered-uint mapping for float atomic max
__device__ __forceinline__ unsigned f2ord(float f) {
    unsigned u = __float_as_uint(f);
    return (u & 0x80000000u) ? ~u : (u | 0x80000000u);
}
__device__ __forceinline__ float ord2f(unsigned m) {
    return (m & 0x80000000u) ? __uint_as_float(m & 0x7FFFFFFFu) : __uint_as_float(~m);
}
__device__ __forceinline__ unsigned short f2bf(float f) {  // RNE fp32->bf16
    unsigned u = __float_as_uint(f);
    return (unsigned short)((u + 0x7FFFu + ((u >> 16) & 1u)) >> 16);
}

// ---- gram: grid(1600) x 256; wave w computes patch blockIdx.x*4+w.
// Emits: G record (fp32, for write pass) + U/V bf16 embeddings (for MFMA max):
//   U = [-2g(9), s, 1, 0...] , V = [g(9), 1, s, 0...]  =>  U.V = d_ij.
__global__ __launch_bounds__(256) void gram_kernel(const float* __restrict__ x,
                                                   float* __restrict__ G,
                                                   unsigned short* __restrict__ U,
                                                   unsigned short* __restrict__ V,
                                                   unsigned* __restrict__ mm) {
    const int t = threadIdx.x;
    if (blockIdx.x == 0 && t == 0) mm[0] = 0u;  // max identity
    const int n = blockIdx.x * 4 + (t >> 6);
    const int l = t & 63;
    const int pi = n / NPS, pj = n % NPS;
    const int r = l >> 2, c = (l & 3) * 4;
    const size_t base = (size_t)(pi * PS + r) * HW + pj * PS + c;
    const float4 A = *(const float4*)(x + base);
    const float4 B = *(const float4*)(x + base + (size_t)HW * HW);
    const float4 C = *(const float4*)(x + base + 2 * (size_t)HW * HW);
    float p[6];
    p[0] = A.x * A.x + A.y * A.y + A.z * A.z + A.w * A.w;
    p[1] = A.x * B.x + A.y * B.y + A.z * B.z + A.w * B.w;
    p[2] = A.x * C.x + A.y * C.y + A.z * C.z + A.w * C.w;
    p[3] = B.x * B.x + B.y * B.y + B.z * B.z + B.w * B.w;
    p[4] = B.x * C.x + B.y * C.y + B.z * C.z + B.w * C.w;
    p[5] = C.x * C.x + C.y * C.y + C.z * C.z + C.w * C.w;
#pragma unroll
    for (int k = 0; k < 6; ++k) {
        float v = p[k];
#pragma unroll
        for (int off = 32; off; off >>= 1) v += __shfl_xor(v, off);
        p[k] = v;
    }
    if (l == 0) {
        const float sc = 1.0f / 768.0f;
        const float g0 = p[0] * sc, g1 = p[1] * sc, g2 = p[2] * sc;
        const float g3 = p[3] * sc, g4 = p[4] * sc, g5 = p[5] * sc;
        const float row[9] = {g0, g1, g2, g1, g3, g4, g2, g4, g5};
        float s = 0.f;
#pragma unroll
        for (int k = 0; k < 9; ++k) s = fmaf(row[k], row[k], s);
        float* dst = G + (size_t)n * GS;
        *(float4*)(dst)     = make_float4(row[0], row[1], row[2], row[3]);
        *(float4*)(dst + 4) = make_float4(row[4], row[5], row[6], row[7]);
        *(float4*)(dst + 8) = make_float4(row[8], s, 0.f, 0.f);
        // bf16 embeddings (16 elems = 32B each)
        unsigned short u16[16], v16[16];
#pragma unroll
        for (int k = 0; k < 9; ++k) { u16[k] = f2bf(-2.f * row[k]); v16[k] = f2bf(row[k]); }
        const unsigned short one = f2bf(1.0f), sb = f2bf(s);
        u16[9] = sb;  u16[10] = one;
        v16[9] = one; v16[10] = sb;
#pragma unroll
        for (int k = 11; k < 16; ++k) { u16[k] = 0; v16[k] = 0; }
        uint4 uw, vw;
        uw.x = u16[0] | (u16[1] << 16); uw.y = u16[2] | (u16[3] << 16);
        uw.z = u16[4] | (u16[5] << 16); uw.w = u16[6] | (u16[7] << 16);
        *(uint4*)(U + (size_t)n * 16) = uw;
        uw.x = u16[8] | (u16[9] << 16); uw.y = u16[10] | (u16[11] << 16);
        uw.z = 0; uw.w = 0;
        *(uint4*)(U + (size_t)n * 16 + 8) = uw;
        vw.x = v16[0] | (v16[1] << 16); vw.y = v16[2] | (v16[3] << 16);
        vw.z = v16[4] | (v16[5] << 16); vw.w = v16[6] | (v16[7] << 16);
        *(uint4*)(V + (size_t)n * 16) = vw;
        vw.x = v16[8] | (v16[9] << 16); vw.y = v16[10] | (v16[11] << 16);
        vw.z = 0; vw.w = 0;
        *(uint4*)(V + (size_t)n * 16 + 8) = vw;
    }
}

// ---- MFMA max: D[32x32] = U_tile . V_tile (K=16), fmax-reduce ALL
// accumulator values (layout-agnostic: full 200x200 tile coverage means any
// A/B transpose confusion permutes but does not change the value set).
#define MMB 2048
__global__ __launch_bounds__(256) void mfma_max_kernel(const unsigned short* __restrict__ U,
                                                       const unsigned short* __restrict__ V,
                                                       unsigned* __restrict__ mm) {
    const int t = threadIdx.x;
    const int w = t >> 6, l = t & 63;
    const int wid = blockIdx.x * 4 + w;
    const int row = l & 31, kg = l >> 5;  // record-in-tile, k-group (8 elems)
    float vmax = -3.4e38f;
    const f32x16 zero = {0.f};
    for (int wt = wid; wt < NT32 * NT32; wt += MMB * 4) {
        const int ti = wt / NT32, tj = wt % NT32;
        const bf16x8 a = *(const bf16x8*)(U + (size_t)(ti * 32 + row) * 16 + kg * 8);
        const bf16x8 b = *(const bf16x8*)(V + (size_t)(tj * 32 + row) * 16 + kg * 8);
        const f32x16 d = __builtin_amdgcn_mfma_f32_32x32x16_bf16(a, b, zero, 0, 0, 0);
#pragma unroll
        for (int k = 0; k < 16; ++k) vmax = fmaxf(vmax, d[k]);
    }
#pragma unroll
    for (int off = 32; off; off >>= 1) vmax = fmaxf(vmax, __shfl_xor(vmax, off));
    __shared__ float smax[4];
    if (l == 0) smax[w] = vmax;
    __syncthreads();
    if (t == 0) {
        const float bm = fmaxf(fmaxf(smax[0], smax[1]), fmaxf(smax[2], smax[3]));
        atomicMax(mm, f2ord(bm));
    }
}

// ---- normalized write (r7 structure, WI 16->32: halves j-record re-reads).
#define WI 32
__global__ __launch_bounds__(320) void write_kernel(const float* __restrict__ G,
                                                    const unsigned* __restrict__ mm,
                                                    float* __restrict__ out) {
    const int t = threadIdx.x;
    const int w = t >> 6, l = t & 63;
    const int i0 = blockIdx.y * WI;
    const int jw = blockIdx.x * 1280 + w * 256 + l * 4;  // lane's 4 cols
    __shared__ float rg[WI * GS];
    if (t < WI * GS / 4)
        ((float4*)rg)[t] = *(const float4*)(G + (size_t)i0 * GS + t * 4);
    float gj[4][10];
#pragma unroll
    for (int c = 0; c < 4; ++c) {
        const float* src = G + (size_t)(jw + c) * GS;
        const float4 a = *(const float4*)(src);
        const float4 b = *(const float4*)(src + 4);
        const float4 q = *(const float4*)(src + 8);
        gj[c][0] = a.x; gj[c][1] = a.y; gj[c][2] = a.z; gj[c][3] = a.w;
        gj[c][4] = b.x; gj[c][5] = b.y; gj[c][6] = b.z; gj[c][7] = b.w;
        gj[c][8] = q.x; gj[c][9] = q.y;
    }
    const float inv = 1.f / ord2f(mm[0]);
    __syncthreads();
    float* dst = out + (size_t)i0 * NP + jw;
#pragma unroll 4
    for (int rr = 0; rr < WI; ++rr) {
        const float4 a = *(const float4*)(rg + rr * GS);
        const float4 b = *(const float4*)(rg + rr * GS + 4);
        const float4 q = *(const float4*)(rg + rr * GS + 8);
        const float gi[9] = {a.x, a.y, a.z, a.w, b.x, b.y, b.z, b.w, q.x};
        const float si = q.y;
        vf4 dv;
#pragma unroll
        for (int c = 0; c < 4; ++c) {
            float inner = 0.f;
#pragma unroll
            for (int k = 0; k < 9; ++k) inner = fmaf(gi[k], gj[c][k], inner);
            dv[c] = (si + gj[c][9] - 2.f * inner) * inv;
        }
        *(vf4*)dst = dv;
        dst += NP;
    }
}

extern "C" void kernel_launch(void* const* d_in, const int* in_sizes, int n_in,
                              void* d_out, int out_size, void* d_ws, size_t ws_size,
                              hipStream_t stream) {
    (void)in_sizes; (void)n_in; (void)out_size; (void)ws_size;
    const float* x = (const float*)d_in[0];
    float* out = (float*)d_out;
    char* ws = (char*)d_ws;
    float* G = (float*)ws;                                   // 307200 B
    unsigned short* U = (unsigned short*)(ws + 307200);      // 204800 B
    unsigned short* V = (unsigned short*)(ws + 512000);      // 204800 B
    unsigned* mm = (unsigned*)(ws + 716800);

    gram_kernel<<<NP / 4, 256, 0, stream>>>(x, G, U, V, mm);
    mfma_max_kernel<<<MMB, 256, 0, stream>>>(U, V, mm);
    write_kernel<<<dim3(5, NP / WI), 320, 0, stream>>>(G, mm, out);
}